// Round 11
// baseline (310.954 us; speedup 1.0000x reference)
//
#include <hip/hip_runtime.h>
#include <hip/hip_bf16.h>

// QuaternionLinear = one 8192x4096x4096 GEMM vs Hamilton-assembled W.
// Round 11: 8 waves + mfma 32x32x16 (faster shape, m119) + kc-major LDS
// [kc][row][32B] (bank-uniform, imm-offset ds_reads, no swizzle needed) +
// asm-pipelined 4-phase tile: {read kc+1 (6x ds_read_b128); lgkmcnt(6);
// sched_barrier; 8 MFMA} so LDS pipe drains under matrix pipe. One barrier
// + vmcnt(0) per tile, classic A+B double buffer staged one tile ahead.

#define M_DIM 8192
#define N_DIM 4096
#define K_DIM 4096
#define BK 64
#define NT (K_DIM / BK)   // 64 K-tiles

typedef __attribute__((ext_vector_type(8))) short bf16x8;
typedef __attribute__((ext_vector_type(4))) float f32x4;
typedef __attribute__((ext_vector_type(16))) float f32x16;
typedef __attribute__((ext_vector_type(8))) unsigned short ushort8;

static __device__ __forceinline__ unsigned short f2bf(float f) {
    unsigned int u = __float_as_uint(f);
    return (unsigned short)((u + 0x7fffu + ((u >> 16) & 1u)) >> 16);
}
static __device__ __forceinline__ unsigned short f2bf_sgn(float f, unsigned int sg) {
    unsigned int u = __float_as_uint(f) ^ sg;
    return (unsigned short)((u + 0x7fffu + ((u >> 16) & 1u)) >> 16);
}

// ---------------- prep: x (fp32) -> xb (bf16) ----------------
__global__ __launch_bounds__(256) void cvt_x_kernel(const float* __restrict__ x,
                                                    unsigned short* __restrict__ xb) {
    int i = (blockIdx.x * 256 + threadIdx.x) * 8;
    f32x4 a = __builtin_nontemporal_load((const f32x4*)(x + i));
    f32x4 b = __builtin_nontemporal_load((const f32x4*)(x + i + 4));
    ushort8 o;
    o[0] = f2bf(a[0]); o[1] = f2bf(a[1]); o[2] = f2bf(a[2]); o[3] = f2bf(a[3]);
    o[4] = f2bf(b[0]); o[5] = f2bf(b[1]); o[6] = f2bf(b[2]); o[7] = f2bf(b[3]);
    *(ushort8*)(xb + i) = o;
}

// ---------------- prep: assemble Hamilton W (bf16) ----------------
__global__ __launch_bounds__(256) void prep_w_kernel(const float* __restrict__ Wr,
    const float* __restrict__ Wi, const float* __restrict__ Wj,
    const float* __restrict__ Wk, unsigned short* __restrict__ wb) {
    int row = blockIdx.x >> 1;
    int col = ((blockIdx.x & 1) * 256 + threadIdx.x) * 8;
    int p = row >> 10, q = col >> 10;
    int ci = p ^ q;
    const float* src = (ci == 0) ? Wr : (ci == 1) ? Wi : (ci == 2) ? Wj : Wk;
    unsigned int sg = ((0x428Eu >> (p * 4 + q)) & 1u) << 31;
    int so = (row & 1023) * 1024 + (col & 1023);
    f32x4 a = *(const f32x4*)(src + so);
    f32x4 b = *(const f32x4*)(src + so + 4);
    ushort8 o;
    o[0] = f2bf_sgn(a[0], sg); o[1] = f2bf_sgn(a[1], sg);
    o[2] = f2bf_sgn(a[2], sg); o[3] = f2bf_sgn(a[3], sg);
    o[4] = f2bf_sgn(b[0], sg); o[5] = f2bf_sgn(b[1], sg);
    o[6] = f2bf_sgn(b[2], sg); o[7] = f2bf_sgn(b[3], sg);
    *(ushort8*)(wb + row * 4096 + col) = o;
}

// ---------------- main GEMM ----------------
#define GLD16(gp, lp) __builtin_amdgcn_global_load_lds( \
    (const __attribute__((address_space(1))) void*)(gp), \
    (__attribute__((address_space(3))) void*)(lp), 16, 0, 0)

#define BAR() do { asm volatile("" ::: "memory"); \
                   __builtin_amdgcn_s_barrier(); \
                   asm volatile("" ::: "memory"); } while (0)
#define VM0() asm volatile("s_waitcnt vmcnt(0)" ::: "memory")
#define SB()  __builtin_amdgcn_sched_barrier(0)
#define LGKM(n) do { asm volatile("s_waitcnt lgkmcnt(" #n ")" ::: "memory"); SB(); } while (0)

#define DSR(dst, addr, imm) \
    asm volatile("ds_read_b128 %0, %1 offset:" imm : "=v"(dst) : "v"(addr))

#define MF32(a, b, c) __builtin_amdgcn_mfma_f32_32x32x16_bf16(a, b, c, 0, 0, 0)

#define DECL6(F) bf16x8 F##a0, F##a1, F##a2, F##a3, F##b0, F##b1
// A imm = kc*8192 + mi*1024 ; B imm = kc*8192 + ni*1024 (vB holds +32768+wn*2048)
#define RD6(F, A0, A1, A2, A3, B0, B1) do { \
    DSR(F##a0, vA, A0); DSR(F##a1, vA, A1); DSR(F##a2, vA, A2); DSR(F##a3, vA, A3); \
    DSR(F##b0, vB, B0); DSR(F##b1, vB, B1); } while (0)

#define MFMA8(F) do { \
    __builtin_amdgcn_s_setprio(1); \
    acc[0][0] = MF32(F##a0, F##b0, acc[0][0]); \
    acc[0][1] = MF32(F##a0, F##b1, acc[0][1]); \
    acc[1][0] = MF32(F##a1, F##b0, acc[1][0]); \
    acc[1][1] = MF32(F##a1, F##b1, acc[1][1]); \
    acc[2][0] = MF32(F##a2, F##b0, acc[2][0]); \
    acc[2][1] = MF32(F##a2, F##b1, acc[2][1]); \
    acc[3][0] = MF32(F##a3, F##b0, acc[3][0]); \
    acc[3][1] = MF32(F##a3, F##b1, acc[3][1]); \
    __builtin_amdgcn_s_setprio(0); \
} while (0)

__global__ __launch_bounds__(512, 2) void qgemm_bf16(
    const unsigned short* __restrict__ A, const unsigned short* __restrict__ B,
    const float* __restrict__ bias, float* __restrict__ out)
{
    // Per buffer (64 KB): A region [kc 4][row 256][32 B] (32 KB), then B
    // region same. Two buffers = 128 KB. Staging chunk c (16B units):
    // kc = c>>9, row = (c>>1)&255, hi = c&1 -> src elem row*4096+kc*16+hi*8.
    __shared__ __align__(16) unsigned short Lsh[65536];

    int bid = blockIdx.x;
    int cpx = gridDim.x >> 3;                 // 512/8 = 64, bijective
    int wg  = (bid & 7) * cpx + (bid >> 3);
    int brow = (wg >> 4) * 256;               // 32 M-tiles
    int bcol = (wg & 15) * 256;               // 16 N-tiles

    int tid  = threadIdx.x;
    int lane = tid & 63;
    int wid  = tid >> 6;                      // 0..7
    int wm   = wid >> 2;                      // 0..1 : 128-row half
    int wn   = wid & 3;                       // 0..3 : 64-col band
    int l31  = lane & 31;
    int hi   = lane >> 5;

    const unsigned short* Ag = A + (size_t)brow * K_DIM;
    const unsigned short* Bg = B + (size_t)bcol * K_DIM;

    unsigned lds0 = (unsigned)(size_t)(__attribute__((address_space(3))) void*)Lsh;
    // read bases (byte): row-part l31*32 + hi*16 ; wave bands in base.
    unsigned vA = lds0 + (unsigned)(wm * 4096 + l31 * 32 + hi * 16);
    unsigned vB = lds0 + 32768u + (unsigned)(wn * 2048 + l31 * 32 + hi * 16);

    // per-thread staging source offsets (elements), t-independent
    int soff[4];
    #pragma unroll
    for (int i = 0; i < 4; ++i) {
        int c = i * 512 + tid;
        soff[i] = ((c >> 1) & 255) * 4096 + (c >> 9) * 16 + (c & 1) * 8;
    }

    f32x16 acc[4][2] = {};

    auto STAGE = [&](int buf, int t) {
        const unsigned short* ga = Ag + t * BK;
        const unsigned short* gb = Bg + t * BK;
        char* l = (char*)Lsh + buf * 65536;
        #pragma unroll
        for (int i = 0; i < 4; ++i)
            GLD16(ga + soff[i], l + (i * 512 + tid) * 16);
        #pragma unroll
        for (int i = 0; i < 4; ++i)
            GLD16(gb + soff[i], l + 32768 + (i * 512 + tid) * 16);
    };

    // Prologue: tile 0 into buf 0.
    STAGE(0, 0);
    VM0(); BAR();

    for (int t = 0; t < NT; ++t) {
        if (t + 1 < NT) STAGE((t & 1) ^ 1, t + 1);

        DECL6(f0); DECL6(f1); DECL6(f2); DECL6(f3);
        RD6(f0, "0", "1024", "2048", "3072", "0", "1024");
        RD6(f1, "8192", "9216", "10240", "11264", "8192", "9216");
        LGKM(6);                 // f0 complete; f1 in flight
        MFMA8(f0);
        RD6(f2, "16384", "17408", "18432", "19456", "16384", "17408");
        LGKM(6);                 // f1 complete; f2 in flight
        MFMA8(f1);
        RD6(f3, "24576", "25600", "26624", "27648", "24576", "25600");
        LGKM(6);                 // f2 complete; f3 in flight
        MFMA8(f2);
        LGKM(0);                 // f3 complete
        MFMA8(f3);

        VM0();                   // tile t+1 staged (issued ~1 tile ago)
        BAR();
        vA ^= 0x10000u; vB ^= 0x10000u;
    }

    // epilogue: 32x32 C/D layout (m74/m101): col = lane&31,
    // row = (reg&3) + 8*(reg>>2) + 4*(lane>>5).
    #pragma unroll
    for (int ni = 0; ni < 2; ++ni) {
        int col = bcol + wn * 64 + ni * 32 + l31;
        float bv = bias[col];
        #pragma unroll
        for (int mi = 0; mi < 4; ++mi) {
            int r0 = brow + wm * 128 + mi * 32 + 4 * hi;
            #pragma unroll
            for (int r = 0; r < 16; ++r) {
                int row = r0 + (r & 3) + 8 * (r >> 2);
                __builtin_nontemporal_store(acc[mi][ni][r] + bv,
                                            &out[(size_t)row * N_DIM + col]);
            }
        }
    }
}

// ---------------- fallback: reg-staged, no workspace (round-3, known-good) --
#define FBM 128
#define FBN 128
#define FBK 64
__global__ __launch_bounds__(256) void qgemm_fb(const float* __restrict__ x,
    const float* __restrict__ Wr, const float* __restrict__ Wi,
    const float* __restrict__ Wj, const float* __restrict__ Wk,
    const float* __restrict__ bias, float* __restrict__ out)
{
    __shared__ unsigned short As[FBM * FBK];
    __shared__ unsigned short Bs[FBN * FBK];

    int bid = blockIdx.x;
    int cpx = gridDim.x >> 3;
    int wg = (bid & 7) * cpx + (bid >> 3);
    int brow = (wg >> 5) * FBM;
    int bcol = (wg & 31) * FBN;

    int tid = threadIdx.x;
    int lane = tid & 63;
    int wv = tid >> 6;
    int wm = (wv >> 1) << 6;
    int wn = (wv & 1) << 6;
    int fr = lane & 15;
    int fk = (lane >> 4) << 3;

    int p = bcol >> 10;
    f32x4 acc[4][4] = {};

    for (int kt = 0; kt < K_DIM / FBK; ++kt) {
        int k0 = kt * FBK;
        int q = k0 >> 10;
        int ci = p ^ q;
        const float* wsrc = (ci == 0) ? Wr : (ci == 1) ? Wi : (ci == 2) ? Wj : Wk;
        unsigned int sg = ((0x428Eu >> (p * 4 + q)) & 1u) << 31;

        __syncthreads();
        #pragma unroll
        for (int i = 0; i < 4; ++i) {
            int c = i * 256 + tid;
            int row = c >> 3, colo = (c & 7) << 3;
            const float* s = x + (size_t)(brow + row) * K_DIM + k0 + colo;
            float4 a = *(const float4*)s;
            float4 b = *(const float4*)(s + 4);
            ushort8 o;
            o[0] = f2bf(a.x); o[1] = f2bf(a.y); o[2] = f2bf(a.z); o[3] = f2bf(a.w);
            o[4] = f2bf(b.x); o[5] = f2bf(b.y); o[6] = f2bf(b.z); o[7] = f2bf(b.w);
            *(ushort8*)(&As[c << 3]) = o;
        }
        #pragma unroll
        for (int i = 0; i < 4; ++i) {
            int c = i * 256 + tid;
            int row = c >> 3, colo = (c & 7) << 3;
            const float* s = wsrc + ((bcol + row) & 1023) * 1024 + ((k0 + colo) & 1023);
            float4 a = *(const float4*)s;
            float4 b = *(const float4*)(s + 4);
            ushort8 o;
            o[0] = f2bf_sgn(a.x, sg); o[1] = f2bf_sgn(a.y, sg);
            o[2] = f2bf_sgn(a.z, sg); o[3] = f2bf_sgn(a.w, sg);
            o[4] = f2bf_sgn(b.x, sg); o[5] = f2bf_sgn(b.y, sg);
            o[6] = f2bf_sgn(b.z, sg); o[7] = f2bf_sgn(b.w, sg);
            *(ushort8*)(&Bs[c << 3]) = o;
        }
        __syncthreads();

        #pragma unroll
        for (int ks = 0; ks < 2; ++ks) {
            bf16x8 af[4], bfr[4];
            #pragma unroll
            for (int m = 0; m < 4; ++m)
                af[m] = *(const bf16x8*)(&As[(wm + m * 16 + fr) * FBK + ks * 32 + fk]);
            #pragma unroll
            for (int n = 0; n < 4; ++n)
                bfr[n] = *(const bf16x8*)(&Bs[(wn + n * 16 + fr) * FBK + ks * 32 + fk]);
            #pragma unroll
            for (int m = 0; m < 4; ++m)
                #pragma unroll
                for (int n = 0; n < 4; ++n)
                    acc[m][n] = __builtin_amdgcn_mfma_f32_16x16x32_bf16(
                        af[m], bfr[n], acc[m][n], 0, 0, 0);
        }
    }

    int cr = (lane >> 4) << 2;
    int cc = lane & 15;
    #pragma unroll
    for (int n = 0; n < 4; ++n) {
        int col = bcol + wn + n * 16 + cc;
        float bv = bias[col];
        #pragma unroll
        for (int m = 0; m < 4; ++m) {
            int r0 = brow + wm + m * 16 + cr;
            #pragma unroll
            for (int r = 0; r < 4; ++r)
                out[(size_t)(r0 + r) * N_DIM + col] = acc[m][n][r] + bv;
        }
    }
}

extern "C" void kernel_launch(void* const* d_in, const int* in_sizes, int n_in,
                              void* d_out, int out_size, void* d_ws, size_t ws_size,
                              hipStream_t stream) {
    const float* x    = (const float*)d_in[0];
    const float* Wr   = (const float*)d_in[1];
    const float* Wi   = (const float*)d_in[2];
    const float* Wj   = (const float*)d_in[3];
    const float* Wk   = (const float*)d_in[4];
    const float* bias = (const float*)d_in[5];
    float* out = (float*)d_out;

    const size_t xb_bytes = (size_t)M_DIM * K_DIM * 2;  // 64 MiB
    const size_t wb_bytes = (size_t)N_DIM * K_DIM * 2;  // 32 MiB

    if (ws_size >= xb_bytes + wb_bytes) {
        unsigned short* xb = (unsigned short*)d_ws;
        unsigned short* wb = (unsigned short*)((char*)d_ws + xb_bytes);
        cvt_x_kernel<<<(M_DIM * K_DIM) / 2048, 256, 0, stream>>>(x, xb);
        prep_w_kernel<<<N_DIM * 2, 256, 0, stream>>>(Wr, Wi, Wj, Wk, wb);
        const int n_blocks = (M_DIM / 256) * (N_DIM / 256);  // 512
        qgemm_bf16<<<n_blocks, 512, 0, stream>>>(xb, wb, bias, out);
    } else {
        const int n_blocks = (M_DIM / FBM) * (N_DIM / FBN);  // 2048
        qgemm_fb<<<n_blocks, 256, 0, stream>>>(x, Wr, Wi, Wj, Wk, bias, out);
    }
}

// Round 12
// 289.761 us; speedup vs baseline: 1.0731x; 1.0731x over previous
//
#include <hip/hip_runtime.h>
#include <hip/hip_bf16.h>

// QuaternionLinear = one 8192x4096x4096 GEMM vs Hamilton-assembled W.
// Round 12: 32x32x16 MFMA (2066 cyc/tile/CU floor, m119-fastest shape;
// fragment layout verified by R11's pass) + the R4-R10 PROVEN 0-conflict
// LDS layout [row][8 x 16B slots, slot = kslot^(row&7)] — R11's kc-major
// layout was an 8-lane-group bank collision (2.5e7 conflicts). Reads:
// per-lane base ^ (kc<<5) + imm mi*4096 (byte-in-row (hi^e0)<<4 | (kc^e1)<<5
// — disjoint bits, so XOR walk is exact). Asm-pipelined 4-phase tile with
// counted lgkmcnt(6) + sched_barrier (rule #18); 1 barrier + vmcnt(0)/tile.

#define M_DIM 8192
#define N_DIM 4096
#define K_DIM 4096
#define BK 64
#define NT (K_DIM / BK)   // 64 K-tiles

typedef __attribute__((ext_vector_type(8))) short bf16x8;
typedef __attribute__((ext_vector_type(4))) float f32x4;
typedef __attribute__((ext_vector_type(16))) float f32x16;
typedef __attribute__((ext_vector_type(8))) unsigned short ushort8;

static __device__ __forceinline__ unsigned short f2bf(float f) {
    unsigned int u = __float_as_uint(f);
    return (unsigned short)((u + 0x7fffu + ((u >> 16) & 1u)) >> 16);
}
static __device__ __forceinline__ unsigned short f2bf_sgn(float f, unsigned int sg) {
    unsigned int u = __float_as_uint(f) ^ sg;
    return (unsigned short)((u + 0x7fffu + ((u >> 16) & 1u)) >> 16);
}

// ---------------- prep: x (fp32) -> xb (bf16) ----------------
__global__ __launch_bounds__(256) void cvt_x_kernel(const float* __restrict__ x,
                                                    unsigned short* __restrict__ xb) {
    int i = (blockIdx.x * 256 + threadIdx.x) * 8;
    f32x4 a = __builtin_nontemporal_load((const f32x4*)(x + i));
    f32x4 b = __builtin_nontemporal_load((const f32x4*)(x + i + 4));
    ushort8 o;
    o[0] = f2bf(a[0]); o[1] = f2bf(a[1]); o[2] = f2bf(a[2]); o[3] = f2bf(a[3]);
    o[4] = f2bf(b[0]); o[5] = f2bf(b[1]); o[6] = f2bf(b[2]); o[7] = f2bf(b[3]);
    *(ushort8*)(xb + i) = o;
}

// ---------------- prep: assemble Hamilton W (bf16) ----------------
__global__ __launch_bounds__(256) void prep_w_kernel(const float* __restrict__ Wr,
    const float* __restrict__ Wi, const float* __restrict__ Wj,
    const float* __restrict__ Wk, unsigned short* __restrict__ wb) {
    int row = blockIdx.x >> 1;
    int col = ((blockIdx.x & 1) * 256 + threadIdx.x) * 8;
    int p = row >> 10, q = col >> 10;
    int ci = p ^ q;
    const float* src = (ci == 0) ? Wr : (ci == 1) ? Wi : (ci == 2) ? Wj : Wk;
    unsigned int sg = ((0x428Eu >> (p * 4 + q)) & 1u) << 31;
    int so = (row & 1023) * 1024 + (col & 1023);
    f32x4 a = *(const f32x4*)(src + so);
    f32x4 b = *(const f32x4*)(src + so + 4);
    ushort8 o;
    o[0] = f2bf_sgn(a[0], sg); o[1] = f2bf_sgn(a[1], sg);
    o[2] = f2bf_sgn(a[2], sg); o[3] = f2bf_sgn(a[3], sg);
    o[4] = f2bf_sgn(b[0], sg); o[5] = f2bf_sgn(b[1], sg);
    o[6] = f2bf_sgn(b[2], sg); o[7] = f2bf_sgn(b[3], sg);
    *(ushort8*)(wb + row * 4096 + col) = o;
}

// ---------------- main GEMM ----------------
#define GLD16(gp, lp) __builtin_amdgcn_global_load_lds( \
    (const __attribute__((address_space(1))) void*)(gp), \
    (__attribute__((address_space(3))) void*)(lp), 16, 0, 0)

#define BAR() do { asm volatile("" ::: "memory"); \
                   __builtin_amdgcn_s_barrier(); \
                   asm volatile("" ::: "memory"); } while (0)
#define VM0() asm volatile("s_waitcnt vmcnt(0)" ::: "memory")
#define SB()  __builtin_amdgcn_sched_barrier(0)
#define LGKM(n) do { asm volatile("s_waitcnt lgkmcnt(" #n ")" ::: "memory"); SB(); } while (0)

#define DSR(dst, addr, imm) \
    asm volatile("ds_read_b128 %0, %1 offset:" imm : "=v"(dst) : "v"(addr))

#define MF32(a, b, c) __builtin_amdgcn_mfma_f32_32x32x16_bf16(a, b, c, 0, 0, 0)

#define DECL6(F) bf16x8 F##a0, F##a1, F##a2, F##a3, F##b0, F##b1
// kc phase: addrA = vA ^ (kc<<5), addrB = vB ^ (kc<<5); A imm = mi*4096,
// B imm = ni*4096.
#define RD6(F, KX) do { \
    unsigned aA_ = vA ^ (KX), aB_ = vB ^ (KX); \
    DSR(F##a0, aA_, "0");     DSR(F##a1, aA_, "4096"); \
    DSR(F##a2, aA_, "8192");  DSR(F##a3, aA_, "12288"); \
    DSR(F##b0, aB_, "0");     DSR(F##b1, aB_, "4096"); } while (0)

#define MFMA8(F) do { \
    __builtin_amdgcn_s_setprio(1); \
    acc[0][0] = MF32(F##a0, F##b0, acc[0][0]); \
    acc[0][1] = MF32(F##a0, F##b1, acc[0][1]); \
    acc[1][0] = MF32(F##a1, F##b0, acc[1][0]); \
    acc[1][1] = MF32(F##a1, F##b1, acc[1][1]); \
    acc[2][0] = MF32(F##a2, F##b0, acc[2][0]); \
    acc[2][1] = MF32(F##a2, F##b1, acc[2][1]); \
    acc[3][0] = MF32(F##a3, F##b0, acc[3][0]); \
    acc[3][1] = MF32(F##a3, F##b1, acc[3][1]); \
    __builtin_amdgcn_s_setprio(0); \
} while (0)

__global__ __launch_bounds__(512, 2) void qgemm_bf16(
    const unsigned short* __restrict__ A, const unsigned short* __restrict__ B,
    const float* __restrict__ bias, float* __restrict__ out)
{
    // Byte map: buf*65536 + ab*32768 + row*128 + slot*16 ; 2 bufs = 128 KB.
    // Content: slot s at row r holds logical kslot s^(r&7) (16B = 8 k-elems),
    // i.e. k-range ((s^(r&7))*8 .. +8) — IDENTICAL content layout to R4-R10
    // (stage formula unchanged, measured 0 conflicts).
    __shared__ __align__(16) unsigned short Lsh[65536];

    int bid = blockIdx.x;
    int cpx = gridDim.x >> 3;                 // 512/8 = 64, bijective
    int wg  = (bid & 7) * cpx + (bid >> 3);
    int brow = (wg >> 4) * 256;               // 32 M-tiles
    int bcol = (wg & 15) * 256;               // 16 N-tiles

    int tid  = threadIdx.x;
    int lane = tid & 63;
    int wid  = tid >> 6;                      // 0..7
    int wm   = wid >> 2;                      // 0..1 : 128-row half of A
    int wn   = wid & 3;                       // 0..3 : 64-col band of B
    int l31  = lane & 31;
    int hi   = lane >> 5;
    unsigned e0 = (unsigned)(l31 & 1);
    unsigned e1 = (unsigned)((l31 >> 1) & 3);

    const unsigned short* Ag = A + (size_t)brow * K_DIM;
    const unsigned short* Bg = B + (size_t)bcol * K_DIM;

    unsigned lds0 = (unsigned)(size_t)(__attribute__((address_space(3))) void*)Lsh;
    // Per-lane read bases (kc=0): row = (wm*128|wn*64) + mi*32 + l31,
    // byte-in-row = ((hi^e0)<<4) + ((0^e1)<<5). Phase kc: ^ (kc<<5).
    unsigned vA = lds0 + (unsigned)(wm * 16384 + l31 * 128)
                + (((unsigned)hi ^ e0) << 4) + (e1 << 5);
    unsigned vB = lds0 + 32768u + (unsigned)(wn * 8192 + l31 * 128)
                + (((unsigned)hi ^ e0) << 4) + (e1 << 5);

    // staging source offsets (elements), t-independent: chunk c = i*512+tid,
    // dest byte = c*16 -> row = c>>3, slot = c&7, src = row*K + (slot^(row&7))*8
    int soff[4];
    #pragma unroll
    for (int i = 0; i < 4; ++i) {
        int c = i * 512 + tid;
        soff[i] = (c >> 3) * K_DIM + (((c & 7) ^ ((c >> 3) & 7)) << 3);
    }

    f32x16 acc[4][2] = {};

    auto STAGE = [&](int buf, int t) {
        const unsigned short* ga = Ag + t * BK;
        const unsigned short* gb = Bg + t * BK;
        char* l = (char*)Lsh + buf * 65536;
        #pragma unroll
        for (int i = 0; i < 4; ++i) {
            GLD16(ga + soff[i], l + (i * 512 + tid) * 16);
            GLD16(gb + soff[i], l + 32768 + (i * 512 + tid) * 16);
        }
    };

    // Prologue: tile 0 into buf 0.
    STAGE(0, 0);
    VM0(); BAR();

    for (int t = 0; t < NT; ++t) {
        if (t + 1 < NT) STAGE((t & 1) ^ 1, t + 1);

        DECL6(f0); DECL6(f1); DECL6(f2); DECL6(f3);
        RD6(f0, 0u);
        RD6(f1, 32u);
        LGKM(6);                 // f0 complete; f1 in flight
        MFMA8(f0);
        RD6(f2, 64u);
        LGKM(6);                 // f1 complete; f2 in flight
        MFMA8(f1);
        RD6(f3, 96u);
        LGKM(6);                 // f2 complete; f3 in flight
        MFMA8(f2);
        LGKM(0);                 // f3 complete
        MFMA8(f3);

        VM0();                   // tile t+1 staged (issued a full tile ago)
        BAR();
        vA ^= 0x10000u; vB ^= 0x10000u;
    }

    // epilogue: 32x32 C/D layout (m74/m101, re-verified by R11 pass):
    // col = lane&31, row = (reg&3) + 8*(reg>>2) + 4*(lane>>5).
    #pragma unroll
    for (int ni = 0; ni < 2; ++ni) {
        int col = bcol + wn * 64 + ni * 32 + l31;
        float bv = bias[col];
        #pragma unroll
        for (int mi = 0; mi < 4; ++mi) {
            int r0 = brow + wm * 128 + mi * 32 + 4 * hi;
            #pragma unroll
            for (int r = 0; r < 16; ++r) {
                int row = r0 + (r & 3) + 8 * (r >> 2);
                __builtin_nontemporal_store(acc[mi][ni][r] + bv,
                                            &out[(size_t)row * N_DIM + col]);
            }
        }
    }
}

// ---------------- fallback: reg-staged, no workspace (round-3, known-good) --
#define FBM 128
#define FBN 128
#define FBK 64
__global__ __launch_bounds__(256) void qgemm_fb(const float* __restrict__ x,
    const float* __restrict__ Wr, const float* __restrict__ Wi,
    const float* __restrict__ Wj, const float* __restrict__ Wk,
    const float* __restrict__ bias, float* __restrict__ out)
{
    __shared__ unsigned short As[FBM * FBK];
    __shared__ unsigned short Bs[FBN * FBK];

    int bid = blockIdx.x;
    int cpx = gridDim.x >> 3;
    int wg = (bid & 7) * cpx + (bid >> 3);
    int brow = (wg >> 5) * FBM;
    int bcol = (wg & 31) * FBN;

    int tid = threadIdx.x;
    int lane = tid & 63;
    int wv = tid >> 6;
    int wm = (wv >> 1) << 6;
    int wn = (wv & 1) << 6;
    int fr = lane & 15;
    int fk = (lane >> 4) << 3;

    int p = bcol >> 10;
    f32x4 acc[4][4] = {};

    for (int kt = 0; kt < K_DIM / FBK; ++kt) {
        int k0 = kt * FBK;
        int q = k0 >> 10;
        int ci = p ^ q;
        const float* wsrc = (ci == 0) ? Wr : (ci == 1) ? Wi : (ci == 2) ? Wj : Wk;
        unsigned int sg = ((0x428Eu >> (p * 4 + q)) & 1u) << 31;

        __syncthreads();
        #pragma unroll
        for (int i = 0; i < 4; ++i) {
            int c = i * 256 + tid;
            int row = c >> 3, colo = (c & 7) << 3;
            const float* s = x + (size_t)(brow + row) * K_DIM + k0 + colo;
            float4 a = *(const float4*)s;
            float4 b = *(const float4*)(s + 4);
            ushort8 o;
            o[0] = f2bf(a.x); o[1] = f2bf(a.y); o[2] = f2bf(a.z); o[3] = f2bf(a.w);
            o[4] = f2bf(b.x); o[5] = f2bf(b.y); o[6] = f2bf(b.z); o[7] = f2bf(b.w);
            *(ushort8*)(&As[c << 3]) = o;
        }
        #pragma unroll
        for (int i = 0; i < 4; ++i) {
            int c = i * 256 + tid;
            int row = c >> 3, colo = (c & 7) << 3;
            const float* s = wsrc + ((bcol + row) & 1023) * 1024 + ((k0 + colo) & 1023);
            float4 a = *(const float4*)s;
            float4 b = *(const float4*)(s + 4);
            ushort8 o;
            o[0] = f2bf_sgn(a.x, sg); o[1] = f2bf_sgn(a.y, sg);
            o[2] = f2bf_sgn(a.z, sg); o[3] = f2bf_sgn(a.w, sg);
            o[4] = f2bf_sgn(b.x, sg); o[5] = f2bf_sgn(b.y, sg);
            o[6] = f2bf_sgn(b.z, sg); o[7] = f2bf_sgn(b.w, sg);
            *(ushort8*)(&Bs[c << 3]) = o;
        }
        __syncthreads();

        #pragma unroll
        for (int ks = 0; ks < 2; ++ks) {
            bf16x8 af[4], bfr[4];
            #pragma unroll
            for (int m = 0; m < 4; ++m)
                af[m] = *(const bf16x8*)(&As[(wm + m * 16 + fr) * FBK + ks * 32 + fk]);
            #pragma unroll
            for (int n = 0; n < 4; ++n)
                bfr[n] = *(const bf16x8*)(&Bs[(wn + n * 16 + fr) * FBK + ks * 32 + fk]);
            #pragma unroll
            for (int m = 0; m < 4; ++m)
                #pragma unroll
                for (int n = 0; n < 4; ++n)
                    acc[m][n] = __builtin_amdgcn_mfma_f32_16x16x32_bf16(
                        af[m], bfr[n], acc[m][n], 0, 0, 0);
        }
    }

    int cr = (lane >> 4) << 2;
    int cc = lane & 15;
    #pragma unroll
    for (int n = 0; n < 4; ++n) {
        int col = bcol + wn + n * 16 + cc;
        float bv = bias[col];
        #pragma unroll
        for (int m = 0; m < 4; ++m) {
            int r0 = brow + wm + m * 16 + cr;
            #pragma unroll
            for (int r = 0; r < 4; ++r)
                out[(size_t)(r0 + r) * N_DIM + col] = acc[m][n][r] + bv;
        }
    }
}

extern "C" void kernel_launch(void* const* d_in, const int* in_sizes, int n_in,
                              void* d_out, int out_size, void* d_ws, size_t ws_size,
                              hipStream_t stream) {
    const float* x    = (const float*)d_in[0];
    const float* Wr   = (const float*)d_in[1];
    const float* Wi   = (const float*)d_in[2];
    const float* Wj   = (const float*)d_in[3];
    const float* Wk   = (const float*)d_in[4];
    const float* bias = (const float*)d_in[5];
    float* out = (float*)d_out;

    const size_t xb_bytes = (size_t)M_DIM * K_DIM * 2;  // 64 MiB
    const size_t wb_bytes = (size_t)N_DIM * K_DIM * 2;  // 32 MiB

    if (ws_size >= xb_bytes + wb_bytes) {
        unsigned short* xb = (unsigned short*)d_ws;
        unsigned short* wb = (unsigned short*)((char*)d_ws + xb_bytes);
        cvt_x_kernel<<<(M_DIM * K_DIM) / 2048, 256, 0, stream>>>(x, xb);
        prep_w_kernel<<<N_DIM * 2, 256, 0, stream>>>(Wr, Wi, Wj, Wk, wb);
        const int n_blocks = (M_DIM / 256) * (N_DIM / 256);  // 512
        qgemm_bf16<<<n_blocks, 512, 0, stream>>>(xb, wb, bias, out);
    } else {
        const int n_blocks = (M_DIM / FBM) * (N_DIM / FBN);  // 2048
        qgemm_fb<<<n_blocks, 256, 0, stream>>>(x, Wr, Wi, Wj, Wk, bias, out);
    }
}